// Round 1
// baseline (226.612 us; speedup 1.0000x reference)
//
#include <hip/hip_runtime.h>

// Problem constants (reference: H=512, WD=512, K=128)
#define PH 512
#define PWD 512
#define PK 128

// Kernel 1: compute s[d] = sum_c (sum_k x[sx_k, sy_k, c]) * W[c, d]
// Single block, 128 threads (2 waves).
__global__ void compute_s_kernel(const float* __restrict__ x,
                                 const float* __restrict__ W,
                                 const int* __restrict__ sid,
                                 float* __restrict__ s_out) {
    __shared__ float colsum_lds[PK];
    const int c = threadIdx.x;  // 0..127

    float colsum = 0.f;
#pragma unroll 8
    for (int k = 0; k < PK; ++k) {
        const int id = sid[k];            // broadcast (wave-uniform) load
        const int sx = id / PH;           // station_ids // H
        const int sy = id % PWD;          // station_ids % WD
        // x[sx, sy, c] — coalesced across the 128 threads
        colsum += x[(size_t)sx * (PWD * PK) + (size_t)sy * PK + c];
    }
    colsum_lds[c] = colsum;
    __syncthreads();

    // s[c] = sum_cc colsum[cc] * W[cc, c]; W reads coalesced across threads,
    // colsum_lds[cc] is a same-address LDS broadcast (conflict-free).
    float s = 0.f;
#pragma unroll 8
    for (int cc = 0; cc < PK; ++cc) {
        s = fmaf(colsum_lds[cc], W[cc * PK + c], s);
    }
    s_out[c] = s;
}

// Kernel 2: broadcast the 128-float vector s across all 512*512 rows.
// Pure streaming stores. Block=256 threads; since 256 % 32 == 0 (32 float4s
// per 128-float period) each thread's d-offset mod 128 is constant across
// its entire grid-stride walk -> load its float4 of s once, then store-only.
__global__ void broadcast_kernel(const float* __restrict__ s,
                                 float4* __restrict__ out,
                                 size_t n4) {
    const int tid = threadIdx.x;
    const float4* s4 = (const float4*)s;
    const float4 v = s4[tid & 31];

    const size_t stride = (size_t)gridDim.x * blockDim.x;
    for (size_t i = (size_t)blockIdx.x * blockDim.x + tid; i < n4; i += stride) {
        out[i] = v;
    }
}

extern "C" void kernel_launch(void* const* d_in, const int* in_sizes, int n_in,
                              void* d_out, int out_size, void* d_ws, size_t ws_size,
                              hipStream_t stream) {
    const float* x   = (const float*)d_in[0];   // (512, 512, 128) f32
    const float* W   = (const float*)d_in[1];   // (128, 128) f32
    const int*   sid = (const int*)d_in[2];     // (128,) int (JAX demotes int64->int32)

    float*  out = (float*)d_out;                // (512, 512, 128) f32
    float*  s_ws = (float*)d_ws;                // 128 floats of scratch

    // Stage 1: tiny reduction -> s (128 floats) in workspace
    compute_s_kernel<<<1, PK, 0, stream>>>(x, W, sid, s_ws);

    // Stage 2: broadcast-fill 128 MiB of output
    const size_t n4 = (size_t)out_size / 4;     // float4 count (out_size % 4 == 0)
    const int block = 256;
    const int grid  = 2048;                     // 256 CU * 8 blocks, grid-stride
    broadcast_kernel<<<grid, block, 0, stream>>>(s_ws, (float4*)out, n4);
}

// Round 2
// 209.698 us; speedup vs baseline: 1.0807x; 1.0807x over previous
//
#include <hip/hip_runtime.h>

// Problem constants (reference: H=512, WD=512, K=128)
#define PH 512
#define PWD 512
#define PK 128

// Stage 1: s[d] = sum_c (sum_k x[sx_k, sy_k, c]) * W[c, d]
// One block, 1024 threads (16 waves) so the gather latencies overlap.
// Thread tid = sub*128 + c handles k (or c) slices {sub, sub+8, ..., sub+120}.
__global__ __launch_bounds__(1024)
void compute_s_kernel(const float* __restrict__ x,
                      const float* __restrict__ W,
                      const int* __restrict__ sid,
                      float* __restrict__ s_out) {
    __shared__ float part[8][PK];
    __shared__ float colsum[PK];

    const int tid = threadIdx.x;
    const int c   = tid & (PK - 1);   // 0..127
    const int sub = tid >> 7;         // 0..7

    // Phase 1: partial column sums over k = sub + 8*m  (16 independent loads)
    float p = 0.f;
#pragma unroll
    for (int m = 0; m < 16; ++m) {
        const int k  = sub + (m << 3);
        const int id = sid[k];
        const int sx = id / PH;
        const int sy = id % PWD;
        p += x[(size_t)(sx * PWD + sy) * PK + c];   // coalesced across c
    }
    part[sub][c] = p;
    __syncthreads();

    if (sub == 0) {
        float t = 0.f;
#pragma unroll
        for (int i = 0; i < 8; ++i) t += part[i][c];
        colsum[c] = t;
    }
    __syncthreads();

    // Phase 2: partial s[d=c] over cc = sub + 8*j  (16 independent W loads)
    float q = 0.f;
#pragma unroll
    for (int j = 0; j < 16; ++j) {
        const int cc = sub + (j << 3);
        q = fmaf(colsum[cc], W[cc * PK + c], q);    // W coalesced across c
    }
    part[sub][c] = q;
    __syncthreads();

    if (sub == 0) {
        float t = 0.f;
#pragma unroll
        for (int i = 0; i < 8; ++i) t += part[i][c];
        s_out[c] = t;
    }
}

// Stage 2: broadcast the 128-float vector s across all 512*512 rows.
// Pure streaming float4 stores; each thread's d-offset mod 128 is constant
// across its grid-stride walk (256 % 32 == 0), so s is loaded once.
__global__ void broadcast_kernel(const float* __restrict__ s,
                                 float4* __restrict__ out,
                                 size_t n4) {
    const int tid = threadIdx.x;
    const float4* s4 = (const float4*)s;
    const float4 v = s4[tid & 31];

    const size_t stride = (size_t)gridDim.x * blockDim.x;
    for (size_t i = (size_t)blockIdx.x * blockDim.x + tid; i < n4; i += stride) {
        out[i] = v;
    }
}

extern "C" void kernel_launch(void* const* d_in, const int* in_sizes, int n_in,
                              void* d_out, int out_size, void* d_ws, size_t ws_size,
                              hipStream_t stream) {
    const float* x   = (const float*)d_in[0];   // (512, 512, 128) f32
    const float* W   = (const float*)d_in[1];   // (128, 128) f32
    const int*   sid = (const int*)d_in[2];     // (128,) int32

    float* out  = (float*)d_out;                // (512, 512, 128) f32
    float* s_ws = (float*)d_ws;                 // 128 floats of scratch

    compute_s_kernel<<<1, 1024, 0, stream>>>(x, W, sid, s_ws);

    const size_t n4 = (size_t)out_size / 4;
    broadcast_kernel<<<2048, 256, 0, stream>>>(s_ws, (float4*)out, n4);
}